// Round 1
// baseline (2977.236 us; speedup 1.0000x reference)
//
#include <hip/hip_runtime.h>

#define V_   50000
#define OOV_ 100
#define VO_  50100
#define E_   128
#define HE_  256
#define HD_  256
#define B_   32
#define S_   256
#define T_   16

static __device__ __forceinline__ float bf2f(unsigned short b) {
  return __uint_as_float(((unsigned)b) << 16);
}
static __device__ __forceinline__ unsigned short f2bf(float f) {
  unsigned u = __float_as_uint(f);
  unsigned r = (u + 0x7fffu + ((u >> 16) & 1u)) >> 16;
  return (unsigned short)r;
}
static __device__ __forceinline__ float sigm(float x) { return 1.f / (1.f + expf(-x)); }

// ---------------- generic fp32 GEMM: C[M,ldC] = act(A[M,K] @ B[K,N] + bias) ----------------
// M multiple of 64, K multiple of 16; N arbitrary (guarded). act: 0=none 1=tanh 2=exp
__global__ __launch_bounds__(256) void gemm_f32(
    const float* __restrict__ A, const float* __restrict__ Bw,
    const float* __restrict__ bias, float* __restrict__ C,
    int M, int N, int K, int ldC, int act)
{
  __shared__ float As[16][64];
  __shared__ float Bs[16][64];
  const int tid = threadIdx.x;
  const int tx = tid & 15, ty = tid >> 4;
  const int row0 = blockIdx.y * 64, col0 = blockIdx.x * 64;
  float acc[4][4] = {{0.f}};
  for (int k0 = 0; k0 < K; k0 += 16) {
#pragma unroll
    for (int q = 0; q < 4; q++) {
      int idx = q * 256 + tid;
      int m = idx >> 4, kk = idx & 15;
      As[kk][m] = A[(size_t)(row0 + m) * K + (k0 + kk)];
      int k2 = idx >> 6, n = idx & 63;
      int cc = col0 + n;
      Bs[k2][n] = (cc < N) ? Bw[(size_t)(k0 + k2) * N + cc] : 0.f;
    }
    __syncthreads();
#pragma unroll
    for (int kk = 0; kk < 16; kk++) {
      float4 a4 = *(const float4*)&As[kk][ty * 4];
      float4 b4 = *(const float4*)&Bs[kk][tx * 4];
      float av[4] = {a4.x, a4.y, a4.z, a4.w};
      float bv[4] = {b4.x, b4.y, b4.z, b4.w};
#pragma unroll
      for (int i = 0; i < 4; i++)
#pragma unroll
        for (int j = 0; j < 4; j++)
          acc[i][j] = fmaf(av[i], bv[j], acc[i][j]);
    }
    __syncthreads();
  }
#pragma unroll
  for (int i = 0; i < 4; i++) {
    int r = row0 + ty * 4 + i;
#pragma unroll
    for (int j = 0; j < 4; j++) {
      int c = col0 + tx * 4 + j;
      if (c < N) {
        float v = acc[i][j] + (bias ? bias[c] : 0.f);
        if (act == 1) v = tanhf(v);
        else if (act == 2) v = expf(v);
        C[(size_t)r * ldC + c] = v;
      }
    }
  }
}

// ---------------- LSTM recurrence: one block per batch element ----------------
// Xpre: (B, steps, 1024) precomputed x@W + b. Upk: (256 k) x (256 j) ushort4 bf16 gate-packed.
__global__ __launch_bounds__(256) void lstm_rec(
    const float* __restrict__ Xpre, const ushort4* __restrict__ Upk,
    const float* __restrict__ h0, const float* __restrict__ c0,
    float* __restrict__ outH, float* __restrict__ hN, float* __restrict__ cN,
    int steps)
{
  __shared__ float hs[256];
  const int b = blockIdx.x, tid = threadIdx.x;
  float c = c0 ? c0[b * 256 + tid] : 0.f;
  hs[tid] = h0 ? h0[b * 256 + tid] : 0.f;
  __syncthreads();
  const float* xp = Xpre + (size_t)b * steps * 1024;
  for (int t = 0; t < steps; t++) {
    float zi = xp[t * 1024 + tid];
    float zf = xp[t * 1024 + 256 + tid];
    float zg = xp[t * 1024 + 512 + tid];
    float zo = xp[t * 1024 + 768 + tid];
#pragma unroll 8
    for (int k = 0; k < 256; k++) {
      float hk = hs[k];
      ushort4 u = Upk[k * 256 + tid];
      zi = fmaf(hk, bf2f(u.x), zi);
      zf = fmaf(hk, bf2f(u.y), zf);
      zg = fmaf(hk, bf2f(u.z), zg);
      zo = fmaf(hk, bf2f(u.w), zo);
    }
    float cn = sigm(zf) * c + sigm(zi) * tanhf(zg);
    float hn = sigm(zo) * tanhf(cn);
    c = cn;
    __syncthreads();
    hs[tid] = hn;
    outH[((size_t)b * steps + t) * 256 + tid] = hn;
    __syncthreads();
  }
  hN[b * 256 + tid] = hs[tid];
  cN[b * 256 + tid] = c;
}

// ---------------- attention: one block per (b,t) ----------------
__global__ __launch_bounds__(256) void attn_kernel(
    const float* __restrict__ dq, const float* __restrict__ enc,
    const int* __restrict__ x_len, float* __restrict__ ctx)
{
  __shared__ float q[256];
  __shared__ float eb[32][256];
  __shared__ float sc[256];
  __shared__ float red[8];
  const int bt = blockIdx.x, tid = threadIdx.x;
  const int b = bt >> 4;
  q[tid] = dq[(size_t)bt * 256 + tid];
  const int len = x_len[b];
  const float* encb = enc + (size_t)b * S_ * 256;
  __syncthreads();
  const int s_loc = tid >> 3, hb = (tid & 7) * 32;
  for (int cch = 0; cch < 8; cch++) {
#pragma unroll
    for (int qq = 0; qq < 32; qq++) {
      int idx = qq * 256 + tid;
      eb[idx >> 8][idx & 255] = encb[(size_t)(cch * 32) * 256 + idx];
    }
    __syncthreads();
    float p = 0.f;
#pragma unroll
    for (int h = 0; h < 32; h++) p = fmaf(q[hb + h], eb[s_loc][hb + h], p);
    p += __shfl_down(p, 4, 8);
    p += __shfl_down(p, 2, 8);
    p += __shfl_down(p, 1, 8);
    if ((tid & 7) == 0) sc[cch * 32 + s_loc] = p;
    __syncthreads();
  }
  float my = (tid < len) ? sc[tid] : -1e30f;
  float m = my;
#pragma unroll
  for (int o = 32; o >= 1; o >>= 1) m = fmaxf(m, __shfl_xor(m, o));
  if ((tid & 63) == 0) red[tid >> 6] = m;
  __syncthreads();
  float bm = fmaxf(fmaxf(red[0], red[1]), fmaxf(red[2], red[3]));
  float e = expf(my - bm);
  float s = e;
#pragma unroll
  for (int o = 32; o >= 1; o >>= 1) s += __shfl_xor(s, o);
  if ((tid & 63) == 0) red[4 + (tid >> 6)] = s;
  __syncthreads();
  float tot = red[4] + red[5] + red[6] + red[7];
  sc[tid] = e / tot;
  __syncthreads();
  float acc = 0.f;
  for (int s2 = 0; s2 < 256; s2++) acc = fmaf(sc[s2], encb[(size_t)s2 * 256 + tid], acc);
  ctx[(size_t)bt * 256 + tid] = acc;
}

// ---------------- copy scores: one block per (b,t) ----------------
__global__ __launch_bounds__(256) void copyseq_kernel(
    const float* __restrict__ at, const float* __restrict__ cp,
    const int* __restrict__ x_len, float* __restrict__ cseq)
{
  __shared__ float q[256];
  __shared__ float eb[32][256];
  __shared__ float sc[256];
  const int bt = blockIdx.x, tid = threadIdx.x;
  const int b = bt >> 4;
  q[tid] = at[(size_t)bt * 256 + tid];
  const int len = x_len[b];
  const float* cpb = cp + (size_t)b * S_ * 256;
  __syncthreads();
  const int s_loc = tid >> 3, hb = (tid & 7) * 32;
  for (int cch = 0; cch < 8; cch++) {
#pragma unroll
    for (int qq = 0; qq < 32; qq++) {
      int idx = qq * 256 + tid;
      eb[idx >> 8][idx & 255] = cpb[(size_t)(cch * 32) * 256 + idx];
    }
    __syncthreads();
    float p = 0.f;
#pragma unroll
    for (int h = 0; h < 32; h++) p = fmaf(q[hb + h], eb[s_loc][hb + h], p);
    p += __shfl_down(p, 4, 8);
    p += __shfl_down(p, 2, 8);
    p += __shfl_down(p, 1, 8);
    if ((tid & 7) == 0) sc[cch * 32 + s_loc] = p;
    __syncthreads();
  }
  cseq[(size_t)bt * 256 + tid] = (tid < len) ? expf(sc[tid]) : 0.f;
}

// ---------------- small kernels ----------------
__global__ void embed_kernel(const int* __restrict__ idx, const float* __restrict__ emb,
                             float* __restrict__ out) {
  int r = blockIdx.x;
  out[(size_t)r * E_ + threadIdx.x] = emb[(size_t)idx[r] * E_ + threadIdx.x];
}
__global__ void packU_kernel(const float* __restrict__ U, ushort4* __restrict__ out) {
  int i = blockIdx.x * 256 + threadIdx.x;  // 65536
  int k = i >> 8, j = i & 255;
  const float* row = U + (size_t)k * 1024;
  ushort4 r;
  r.x = f2bf(row[j]);       r.y = f2bf(row[j + 256]);
  r.z = f2bf(row[j + 512]); r.w = f2bf(row[j + 768]);
  out[i] = r;
}
__global__ void concat_kernel(const float* __restrict__ ctx, const float* __restrict__ dec,
                              float* __restrict__ cat) {
  int i = blockIdx.x * 256 + threadIdx.x;  // 512*512
  int r = i >> 9, j = i & 511;
  cat[i] = (j < 256) ? ctx[r * 256 + j] : dec[r * 256 + (j - 256)];
}
__global__ void pad_kernel(float* __restrict__ out) {
  int i = blockIdx.x * 256 + threadIdx.x;  // 51200
  if (i < B_ * T_ * OOV_) {
    int bt = i / OOV_, j = i - bt * OOV_;
    out[(size_t)bt * VO_ + V_ + j] = 1e-10f;
  }
}
__global__ void scatter_kernel(const float* __restrict__ cseq, const int* __restrict__ xoov,
                               float* __restrict__ out) {
  int i = blockIdx.x * 256 + threadIdx.x;  // 131072
  int bt = i >> 8, s = i & 255, b = bt >> 4;
  float v = cseq[i];
  if (v != 0.f) atomicAdd(&out[(size_t)bt * VO_ + xoov[b * S_ + s]], v);
}
__global__ __launch_bounds__(256) void rowsum_kernel(const float* __restrict__ out,
                                                     float* __restrict__ rowlog) {
  __shared__ float red[256];
  int bt = blockIdx.x, tid = threadIdx.x;
  const float* row = out + (size_t)bt * VO_;
  float s = 0.f;
  for (int i = tid; i < VO_; i += 256) s += row[i];
  red[tid] = s;
  __syncthreads();
  for (int o = 128; o >= 1; o >>= 1) {
    if (tid < o) red[tid] += red[tid + o];
    __syncthreads();
  }
  if (tid == 0) rowlog[bt] = logf(red[0]);
}
__global__ void finalize_kernel(float* __restrict__ out, const float* __restrict__ rowlog) {
  size_t i = (size_t)blockIdx.x * 256 + threadIdx.x;
  if (i < (size_t)B_ * T_ * VO_) {
    int bt = (int)(i / VO_);
    out[i] = logf(out[i]) - rowlog[bt];
  }
}

extern "C" void kernel_launch(void* const* d_in, const int* in_sizes, int n_in,
                              void* d_out, int out_size, void* d_ws, size_t ws_size,
                              hipStream_t stream) {
  const int*   x     = (const int*)d_in[0];
  const int*   xoov  = (const int*)d_in[1];
  const int*   xlen  = (const int*)d_in[2];
  const int*   decx  = (const int*)d_in[3];
  const float* emb   = (const float*)d_in[4];
  const float* Wenc  = (const float*)d_in[5];
  const float* Uenc  = (const float*)d_in[6];
  const float* benc  = (const float*)d_in[7];
  const float* We2d  = (const float*)d_in[8];
  const float* be2d  = (const float*)d_in[9];
  const float* Wdec  = (const float*)d_in[10];
  const float* Udec  = (const float*)d_in[11];
  const float* bdec  = (const float*)d_in[12];
  const float* Wattn = (const float*)d_in[13];
  const float* Wout  = (const float*)d_in[14];
  const float* bout  = (const float*)d_in[15];
  const float* Wgen  = (const float*)d_in[16];
  const float* Wcopy = (const float*)d_in[17];
  const float* bcopy = (const float*)d_in[18];
  float* out = (float*)d_out;
  float* ws  = (float*)d_ws;

  // workspace layout (float offsets)
  float* Xenc   = ws + 0;            // 8,388,608  (reused as cp after encoder)
  float* scra   = ws + 8388608;      // 1,048,576 scratch region
  float* xemb   = scra;              // dead after pre-GEMMs
  float* dqb    = scra + 0;          // 131072
  float* ctxb   = scra + 131072;     // 131072
  float* catb   = scra + 262144;     // 262144
  float* attno  = scra + 524288;     // 131072
  float* cseq   = scra + 655360;     // 131072
  float* rowlog = scra + 786432;     // 512
  float* demb   = ws + 9437184;      // 65536
  float* Xdec   = ws + 9502720;      // 524288
  ushort4* UpkE = (ushort4*)(ws + 10027008);  // 65536 x 8B
  ushort4* UpkD = (ushort4*)(ws + 10158080);
  float* encO   = ws + 10289152;     // 2,097,152
  float* ehc    = ws + 12386304;     // 16384 (rows 0..31 = eh, 32..63 = ec)
  float* h0c0   = ws + 12402688;     // 16384
  float* decO   = ws + 12419072;     // 131072
  float* cp     = ws + 0;            // reuse Xenc region

  float* sh  = out + (size_t)B_ * T_ * VO_;
  float* scf = sh + B_ * HD_;

  hipLaunchKernelGGL(packU_kernel, dim3(256), dim3(256), 0, stream, Uenc, UpkE);
  hipLaunchKernelGGL(packU_kernel, dim3(256), dim3(256), 0, stream, Udec, UpkD);
  hipLaunchKernelGGL(embed_kernel, dim3(B_ * S_), dim3(E_), 0, stream, x, emb, xemb);
  hipLaunchKernelGGL(embed_kernel, dim3(B_ * T_), dim3(E_), 0, stream, decx, emb, demb);
  hipLaunchKernelGGL(gemm_f32, dim3(16, 128), dim3(256), 0, stream,
                     xemb, Wenc, benc, Xenc, B_ * S_, 1024, 128, 1024, 0);
  hipLaunchKernelGGL(gemm_f32, dim3(16, 8), dim3(256), 0, stream,
                     demb, Wdec, bdec, Xdec, B_ * T_, 1024, 128, 1024, 0);
  hipLaunchKernelGGL(lstm_rec, dim3(B_), dim3(256), 0, stream,
                     Xenc, UpkE, (const float*)nullptr, (const float*)nullptr,
                     encO, ehc, ehc + 32 * 256, S_);
  hipLaunchKernelGGL(gemm_f32, dim3(4, 1), dim3(256), 0, stream,
                     ehc, We2d, be2d, h0c0, 64, 256, 256, 256, 0);
  hipLaunchKernelGGL(lstm_rec, dim3(B_), dim3(256), 0, stream,
                     Xdec, UpkD, h0c0, h0c0 + 32 * 256, decO, sh, scf, T_);
  hipLaunchKernelGGL(gemm_f32, dim3(4, 8), dim3(256), 0, stream,
                     decO, Wattn, (const float*)nullptr, dqb, B_ * T_, 256, 256, 256, 0);
  hipLaunchKernelGGL(attn_kernel, dim3(B_ * T_), dim3(256), 0, stream, dqb, encO, xlen, ctxb);
  hipLaunchKernelGGL(concat_kernel, dim3(1024), dim3(256), 0, stream, ctxb, decO, catb);
  hipLaunchKernelGGL(gemm_f32, dim3(4, 8), dim3(256), 0, stream,
                     catb, Wout, bout, attno, B_ * T_, 256, 512, 256, 1);
  hipLaunchKernelGGL(gemm_f32, dim3(4, 128), dim3(256), 0, stream,
                     encO, Wcopy, bcopy, cp, B_ * S_, 256, 256, 256, 1);
  hipLaunchKernelGGL(gemm_f32, dim3(782, 8), dim3(256), 0, stream,
                     attno, Wgen, (const float*)nullptr, out, B_ * T_, V_, 256, VO_, 2);
  hipLaunchKernelGGL(pad_kernel, dim3(200), dim3(256), 0, stream, out);
  hipLaunchKernelGGL(copyseq_kernel, dim3(B_ * T_), dim3(256), 0, stream, attno, cp, xlen, cseq);
  hipLaunchKernelGGL(scatter_kernel, dim3(512), dim3(256), 0, stream, cseq, xoov, out);
  hipLaunchKernelGGL(rowsum_kernel, dim3(B_ * T_), dim3(256), 0, stream, out, rowlog);
  hipLaunchKernelGGL(finalize_kernel, dim3((B_ * T_ * VO_ + 255) / 256), dim3(256), 0, stream,
                     out, rowlog);
}

// Round 2
// 1262.186 us; speedup vs baseline: 2.3588x; 2.3588x over previous
//
#include <hip/hip_runtime.h>

#define V_   50000
#define OOV_ 100
#define VO_  50100
#define E_   128
#define HE_  256
#define HD_  256
#define B_   32
#define S_   256
#define T_   16

typedef _Float16 h2_t __attribute__((ext_vector_type(2)));
typedef __attribute__((ext_vector_type(8))) short bfrag_t;
typedef __attribute__((ext_vector_type(4))) float f32x4;

union U32H2 { unsigned u; h2_t h; };
union FRAG  { uint4 u; bfrag_t s; };

static __device__ __forceinline__ float bf2f(unsigned short b) {
  return __uint_as_float(((unsigned)b) << 16);
}
static __device__ __forceinline__ unsigned short f2bf(float f) {
  unsigned u = __float_as_uint(f);
  unsigned r = (u + 0x7fffu + ((u >> 16) & 1u)) >> 16;
  return (unsigned short)r;
}
static __device__ __forceinline__ unsigned pk2bf(float a, float b) {
  return ((unsigned)f2bf(b) << 16) | (unsigned)f2bf(a);
}
static __device__ __forceinline__ float sigm(float x) { return 1.f / (1.f + expf(-x)); }

static __device__ __forceinline__ float dot2u(unsigned upair, unsigned hpairv, float acc) {
  U32H2 a; a.u = upair;
  U32H2 b; b.u = hpairv;
#if __has_builtin(__builtin_amdgcn_fdot2)
  return __builtin_amdgcn_fdot2(a.h, b.h, acc, false);
#else
  acc = fmaf((float)a.h.x, (float)b.h.x, acc);
  return fmaf((float)a.h.y, (float)b.h.y, acc);
#endif
}

// ---------------- generic fp32 GEMM: C[M,ldC] = act(A[M,K] @ B[K,N] + bias) ----------------
__global__ __launch_bounds__(256) void gemm_f32(
    const float* __restrict__ A, const float* __restrict__ Bw,
    const float* __restrict__ bias, float* __restrict__ C,
    int M, int N, int K, int ldC, int act)
{
  __shared__ float As[16][64];
  __shared__ float Bs[16][64];
  const int tid = threadIdx.x;
  const int tx = tid & 15, ty = tid >> 4;
  const int row0 = blockIdx.y * 64, col0 = blockIdx.x * 64;
  float acc[4][4] = {{0.f}};
  for (int k0 = 0; k0 < K; k0 += 16) {
#pragma unroll
    for (int q = 0; q < 4; q++) {
      int idx = q * 256 + tid;
      int m = idx >> 4, kk = idx & 15;
      As[kk][m] = A[(size_t)(row0 + m) * K + (k0 + kk)];
      int k2 = idx >> 6, n = idx & 63;
      int cc = col0 + n;
      Bs[k2][n] = (cc < N) ? Bw[(size_t)(k0 + k2) * N + cc] : 0.f;
    }
    __syncthreads();
#pragma unroll
    for (int kk = 0; kk < 16; kk++) {
      float4 a4 = *(const float4*)&As[kk][ty * 4];
      float4 b4 = *(const float4*)&Bs[kk][tx * 4];
      float av[4] = {a4.x, a4.y, a4.z, a4.w};
      float bv[4] = {b4.x, b4.y, b4.z, b4.w};
#pragma unroll
      for (int i = 0; i < 4; i++)
#pragma unroll
        for (int j = 0; j < 4; j++)
          acc[i][j] = fmaf(av[i], bv[j], acc[i][j]);
    }
    __syncthreads();
  }
#pragma unroll
  for (int i = 0; i < 4; i++) {
    int r = row0 + ty * 4 + i;
#pragma unroll
    for (int j = 0; j < 4; j++) {
      int c = col0 + tx * 4 + j;
      if (c < N) {
        float v = acc[i][j] + (bias ? bias[c] : 0.f);
        if (act == 1) v = tanhf(v);
        else if (act == 2) v = expf(v);
        C[(size_t)r * ldC + c] = v;
      }
    }
  }
}

// ---------------- LSTM v2: 1 block/batch, 1024 thr, U resident (96 VGPR + 128KB LDS) ------
// Upk2: [128 k-pairs][1024 cols] of packed f16 pairs (U[2p][c], U[2p+1][c]).
// thread (jg=tid>>3, kq=tid&7): cols jg*8..+8, k in [kq*32, kq*32+32).
#define DOT8(u0, u1, hpi)                \
  acc[0] = dot2u(u0.x, hpi, acc[0]);     \
  acc[1] = dot2u(u0.y, hpi, acc[1]);     \
  acc[2] = dot2u(u0.z, hpi, acc[2]);     \
  acc[3] = dot2u(u0.w, hpi, acc[3]);     \
  acc[4] = dot2u(u1.x, hpi, acc[4]);     \
  acc[5] = dot2u(u1.y, hpi, acc[5]);     \
  acc[6] = dot2u(u1.z, hpi, acc[6]);     \
  acc[7] = dot2u(u1.w, hpi, acc[7]);

__global__ __launch_bounds__(1024) void lstm_rec2(
    const float* __restrict__ Xpre, const unsigned* __restrict__ Upk2,
    const float* __restrict__ h0, const float* __restrict__ c0,
    float* __restrict__ outH, float* __restrict__ hN, float* __restrict__ cN,
    int steps)
{
  __shared__ unsigned ldsU[32 * 1028];   // 128.5 KB: 4 LDS pair-rows per kq, stride 1028
  __shared__ float zpart[4 * 1028];      // 16.4 KB
  __shared__ unsigned hpair[128];        // h as f16 pairs
  const int tid = threadIdx.x, b = blockIdx.x;
  const int jg = tid >> 3, kq = tid & 7;

  // load U: 12 pair-rows to regs, 4 to LDS
  uint4 Ur[24];
  const unsigned* ubase = Upk2 + jg * 8;
#pragma unroll
  for (int i = 0; i < 12; i++) {
    int p = kq * 16 + i;
    Ur[2 * i]     = *(const uint4*)(ubase + p * 1024);
    Ur[2 * i + 1] = *(const uint4*)(ubase + p * 1024 + 4);
  }
#pragma unroll
  for (int i = 0; i < 4; i++) {
    int p = kq * 16 + 12 + i;
    uint4 q0 = *(const uint4*)(ubase + p * 1024);
    uint4 q1 = *(const uint4*)(ubase + p * 1024 + 4);
    *(uint4*)&ldsU[(kq * 4 + i) * 1028 + jg * 8] = q0;
    *(uint4*)&ldsU[(kq * 4 + i) * 1028 + jg * 8 + 4] = q1;
  }
  float c = 0.f, hcur = 0.f;
  if (tid < 256) {
    c    = c0 ? c0[b * 256 + tid] : 0.f;
    hcur = h0 ? h0[b * 256 + tid] : 0.f;
  }
  if (tid < 128) {
    float a  = h0 ? h0[b * 256 + 2 * tid] : 0.f;
    float b2 = h0 ? h0[b * 256 + 2 * tid + 1] : 0.f;
    U32H2 cv; cv.h = h2_t{(_Float16)a, (_Float16)b2};
    hpair[tid] = cv.u;
  }
  __syncthreads();

  const float* xp = Xpre + (size_t)b * steps * 1024;
  const unsigned* myld = &ldsU[kq * 4 * 1028 + jg * 8];

  for (int t = 0; t < steps; t++) {
    // updater threads issue this step's X loads early (hidden under dot phase)
    float x0 = 0.f, x1 = 0.f, x2 = 0.f, x3 = 0.f;
    if (tid < 256) {
      x0 = xp[t * 1024 + tid];
      x1 = xp[t * 1024 + 256 + tid];
      x2 = xp[t * 1024 + 512 + tid];
      x3 = xp[t * 1024 + 768 + tid];
    }
    float acc[8] = {0.f, 0.f, 0.f, 0.f, 0.f, 0.f, 0.f, 0.f};
    {
      uint4 hA = *(const uint4*)&hpair[kq * 16];
      DOT8(Ur[0], Ur[1], hA.x)  DOT8(Ur[2], Ur[3], hA.y)
      DOT8(Ur[4], Ur[5], hA.z)  DOT8(Ur[6], Ur[7], hA.w)
    }
    {
      uint4 hB = *(const uint4*)&hpair[kq * 16 + 4];
      DOT8(Ur[8], Ur[9], hB.x)   DOT8(Ur[10], Ur[11], hB.y)
      DOT8(Ur[12], Ur[13], hB.z) DOT8(Ur[14], Ur[15], hB.w)
    }
    {
      uint4 hC = *(const uint4*)&hpair[kq * 16 + 8];
      DOT8(Ur[16], Ur[17], hC.x) DOT8(Ur[18], Ur[19], hC.y)
      DOT8(Ur[20], Ur[21], hC.z) DOT8(Ur[22], Ur[23], hC.w)
    }
    {
      uint4 hD = *(const uint4*)&hpair[kq * 16 + 12];
      unsigned hh[4] = {hD.x, hD.y, hD.z, hD.w};
#pragma unroll
      for (int r = 0; r < 4; r++) {
        uint4 u0 = *(const uint4*)(myld + r * 1028);
        uint4 u1 = *(const uint4*)(myld + r * 1028 + 4);
        unsigned hpi = hh[r];
        DOT8(u0, u1, hpi)
      }
    }
    // pair-reduce kq<->kq^1 (adjacent lanes), halved zpart
#pragma unroll
    for (int g = 0; g < 8; g++) acc[g] += __shfl_xor(acc[g], 1);
    if ((kq & 1) == 0) {
      int r = kq >> 1;
      *(float4*)&zpart[r * 1028 + jg * 8]     = make_float4(acc[0], acc[1], acc[2], acc[3]);
      *(float4*)&zpart[r * 1028 + jg * 8 + 4] = make_float4(acc[4], acc[5], acc[6], acc[7]);
    }
    __syncthreads();
    if (tid < 256) {
      int j = tid;
      float s0 = 0.f, s1 = 0.f, s2 = 0.f, s3 = 0.f;
#pragma unroll
      for (int r = 0; r < 4; r++) {
        s0 += zpart[r * 1028 + j];
        s1 += zpart[r * 1028 + 256 + j];
        s2 += zpart[r * 1028 + 512 + j];
        s3 += zpart[r * 1028 + 768 + j];
      }
      float zi = x0 + s0, zf = x1 + s1, zg = x2 + s2, zo = x3 + s3;
      c = sigm(zf) * c + sigm(zi) * tanhf(zg);
      hcur = sigm(zo) * tanhf(c);
      outH[((size_t)b * steps + t) * 256 + j] = hcur;
      float hother = __shfl_xor(hcur, 1);
      if ((j & 1) == 0) {
        U32H2 cv; cv.h = h2_t{(_Float16)hcur, (_Float16)hother};
        hpair[j >> 1] = cv.u;
      }
    }
    __syncthreads();
  }
  if (tid < 256) {
    hN[b * 256 + tid] = hcur;
    cN[b * 256 + tid] = c;
  }
}

// ---------------- gen = exp(attn_out @ Wgen) via bf16 MFMA ----------------
// Abf: [512][256] bf16 (k-contig). Wgen fp32 [256][50000] loaded strided + packed in-reg.
__global__ __launch_bounds__(256) void gen_mfma(
    const unsigned short* __restrict__ Abf, const float* __restrict__ Wgen,
    float* __restrict__ out)
{
  const int w = threadIdx.x >> 6, lane = threadIdx.x & 63;
  const int m0 = blockIdx.y * 64 + w * 16;
  const int n0 = blockIdx.x * 64;
  const int l16 = lane & 15, lq = lane >> 4;
  f32x4 acc[4] = {f32x4{0,0,0,0}, f32x4{0,0,0,0}, f32x4{0,0,0,0}, f32x4{0,0,0,0}};
  for (int k0 = 0; k0 < 256; k0 += 32) {
    FRAG a;
    a.u = *(const uint4*)(Abf + (size_t)(m0 + l16) * 256 + k0 + lq * 8);
#pragma unroll
    for (int ns = 0; ns < 4; ns++) {
      int n = n0 + ns * 16 + l16;
      int nc = n < V_ ? n : V_ - 1;
      const float* bp = Wgen + (size_t)(k0 + lq * 8) * V_ + nc;
      FRAG bf;
      bf.u.x = pk2bf(bp[0],          bp[(size_t)V_]);
      bf.u.y = pk2bf(bp[2 * (size_t)V_], bp[3 * (size_t)V_]);
      bf.u.z = pk2bf(bp[4 * (size_t)V_], bp[5 * (size_t)V_]);
      bf.u.w = pk2bf(bp[6 * (size_t)V_], bp[7 * (size_t)V_]);
      acc[ns] = __builtin_amdgcn_mfma_f32_16x16x32_bf16(a.s, bf.s, acc[ns], 0, 0, 0);
    }
  }
#pragma unroll
  for (int ns = 0; ns < 4; ns++) {
    int col = n0 + ns * 16 + l16;
    if (col < V_) {
#pragma unroll
      for (int r = 0; r < 4; r++) {
        int row = m0 + lq * 4 + r;           // C/D: col=lane&15, row=(lane>>4)*4+reg
        out[(size_t)row * VO_ + col] = expf(acc[ns][r]);
      }
    }
  }
}

// ---------------- attention: one block per (b,t) ----------------
__global__ __launch_bounds__(256) void attn_kernel(
    const float* __restrict__ dq, const float* __restrict__ enc,
    const int* __restrict__ x_len, float* __restrict__ ctx)
{
  __shared__ float q[256];
  __shared__ float eb[32][256];
  __shared__ float sc[256];
  __shared__ float red[8];
  const int bt = blockIdx.x, tid = threadIdx.x;
  const int b = bt >> 4;
  q[tid] = dq[(size_t)bt * 256 + tid];
  const int len = x_len[b];
  const float* encb = enc + (size_t)b * S_ * 256;
  __syncthreads();
  const int s_loc = tid >> 3, hb = (tid & 7) * 32;
  for (int cch = 0; cch < 8; cch++) {
#pragma unroll
    for (int qq = 0; qq < 32; qq++) {
      int idx = qq * 256 + tid;
      eb[idx >> 8][idx & 255] = encb[(size_t)(cch * 32) * 256 + idx];
    }
    __syncthreads();
    float p = 0.f;
#pragma unroll
    for (int h = 0; h < 32; h++) p = fmaf(q[hb + h], eb[s_loc][hb + h], p);
    p += __shfl_down(p, 4, 8);
    p += __shfl_down(p, 2, 8);
    p += __shfl_down(p, 1, 8);
    if ((tid & 7) == 0) sc[cch * 32 + s_loc] = p;
    __syncthreads();
  }
  float my = (tid < len) ? sc[tid] : -1e30f;
  float m = my;
#pragma unroll
  for (int o = 32; o >= 1; o >>= 1) m = fmaxf(m, __shfl_xor(m, o));
  if ((tid & 63) == 0) red[tid >> 6] = m;
  __syncthreads();
  float bm = fmaxf(fmaxf(red[0], red[1]), fmaxf(red[2], red[3]));
  float e = expf(my - bm);
  float s = e;
#pragma unroll
  for (int o = 32; o >= 1; o >>= 1) s += __shfl_xor(s, o);
  if ((tid & 63) == 0) red[4 + (tid >> 6)] = s;
  __syncthreads();
  float tot = red[4] + red[5] + red[6] + red[7];
  sc[tid] = e / tot;
  __syncthreads();
  float acc = 0.f;
  for (int s2 = 0; s2 < 256; s2++) acc = fmaf(sc[s2], encb[(size_t)s2 * 256 + tid], acc);
  ctx[(size_t)bt * 256 + tid] = acc;
}

// ---------------- copy scores: one block per (b,t) ----------------
__global__ __launch_bounds__(256) void copyseq_kernel(
    const float* __restrict__ at, const float* __restrict__ cp,
    const int* __restrict__ x_len, float* __restrict__ cseq)
{
  __shared__ float q[256];
  __shared__ float eb[32][256];
  __shared__ float sc[256];
  const int bt = blockIdx.x, tid = threadIdx.x;
  const int b = bt >> 4;
  q[tid] = at[(size_t)bt * 256 + tid];
  const int len = x_len[b];
  const float* cpb = cp + (size_t)b * S_ * 256;
  __syncthreads();
  const int s_loc = tid >> 3, hb = (tid & 7) * 32;
  for (int cch = 0; cch < 8; cch++) {
#pragma unroll
    for (int qq = 0; qq < 32; qq++) {
      int idx = qq * 256 + tid;
      eb[idx >> 8][idx & 255] = cpb[(size_t)(cch * 32) * 256 + idx];
    }
    __syncthreads();
    float p = 0.f;
#pragma unroll
    for (int h = 0; h < 32; h++) p = fmaf(q[hb + h], eb[s_loc][hb + h], p);
    p += __shfl_down(p, 4, 8);
    p += __shfl_down(p, 2, 8);
    p += __shfl_down(p, 1, 8);
    if ((tid & 7) == 0) sc[cch * 32 + s_loc] = p;
    __syncthreads();
  }
  cseq[(size_t)bt * 256 + tid] = (tid < len) ? expf(sc[tid]) : 0.f;
}

// ---------------- small kernels ----------------
__global__ void embed_kernel(const int* __restrict__ idx, const float* __restrict__ emb,
                             float* __restrict__ out) {
  int r = blockIdx.x;
  out[(size_t)r * E_ + threadIdx.x] = emb[(size_t)idx[r] * E_ + threadIdx.x];
}
__global__ void packU2_kernel(const float* __restrict__ U, unsigned* __restrict__ out) {
  int i = blockIdx.x * 256 + threadIdx.x;  // 131072 = 128 pairs * 1024 cols
  int p = i >> 10, col = i & 1023;
  float a = U[(size_t)(2 * p) * 1024 + col];
  float b = U[(size_t)(2 * p + 1) * 1024 + col];
  U32H2 cv; cv.h = h2_t{(_Float16)a, (_Float16)b};
  out[i] = cv.u;
}
__global__ void f2bf_kernel(const float* __restrict__ in, unsigned short* __restrict__ out, int n) {
  int i = blockIdx.x * 256 + threadIdx.x;
  if (i < n) out[i] = f2bf(in[i]);
}
__global__ void concat_kernel(const float* __restrict__ ctx, const float* __restrict__ dec,
                              float* __restrict__ cat) {
  int i = blockIdx.x * 256 + threadIdx.x;  // 512*512
  int r = i >> 9, j = i & 511;
  cat[i] = (j < 256) ? ctx[r * 256 + j] : dec[r * 256 + (j - 256)];
}
__global__ void pad_kernel(float* __restrict__ out) {
  int i = blockIdx.x * 256 + threadIdx.x;  // 51200
  if (i < B_ * T_ * OOV_) {
    int bt = i / OOV_, j = i - bt * OOV_;
    out[(size_t)bt * VO_ + V_ + j] = 1e-10f;
  }
}
__global__ void scatter_kernel(const float* __restrict__ cseq, const int* __restrict__ xoov,
                               float* __restrict__ out) {
  int i = blockIdx.x * 256 + threadIdx.x;  // 131072
  int bt = i >> 8, s = i & 255, b = bt >> 4;
  float v = cseq[i];
  if (v != 0.f) atomicAdd(&out[(size_t)bt * VO_ + xoov[b * S_ + s]], v);
}
__global__ __launch_bounds__(256) void rowsum_kernel(const float* __restrict__ out,
                                                     float* __restrict__ rowlog) {
  __shared__ float red[256];
  int bt = blockIdx.x, tid = threadIdx.x;
  const float* row = out + (size_t)bt * VO_;
  float s = 0.f;
  for (int i = tid; i < VO_; i += 256) s += row[i];
  red[tid] = s;
  __syncthreads();
  for (int o = 128; o >= 1; o >>= 1) {
    if (tid < o) red[tid] += red[tid + o];
    __syncthreads();
  }
  if (tid == 0) rowlog[bt] = logf(red[0]);
}
__global__ void finalize_kernel(float* __restrict__ out, const float* __restrict__ rowlog) {
  size_t i = (size_t)blockIdx.x * 256 + threadIdx.x;
  if (i < (size_t)B_ * T_ * VO_) {
    int bt = (int)(i / VO_);
    out[i] = logf(out[i]) - rowlog[bt];
  }
}

extern "C" void kernel_launch(void* const* d_in, const int* in_sizes, int n_in,
                              void* d_out, int out_size, void* d_ws, size_t ws_size,
                              hipStream_t stream) {
  const int*   x     = (const int*)d_in[0];
  const int*   xoov  = (const int*)d_in[1];
  const int*   xlen  = (const int*)d_in[2];
  const int*   decx  = (const int*)d_in[3];
  const float* emb   = (const float*)d_in[4];
  const float* Wenc  = (const float*)d_in[5];
  const float* Uenc  = (const float*)d_in[6];
  const float* benc  = (const float*)d_in[7];
  const float* We2d  = (const float*)d_in[8];
  const float* be2d  = (const float*)d_in[9];
  const float* Wdec  = (const float*)d_in[10];
  const float* Udec  = (const float*)d_in[11];
  const float* bdec  = (const float*)d_in[12];
  const float* Wattn = (const float*)d_in[13];
  const float* Wout  = (const float*)d_in[14];
  const float* bout  = (const float*)d_in[15];
  const float* Wgen  = (const float*)d_in[16];
  const float* Wcopy = (const float*)d_in[17];
  const float* bcopy = (const float*)d_in[18];
  float* out = (float*)d_out;
  float* ws  = (float*)d_ws;

  // workspace layout (float offsets) — identical footprint to R1 (≈50.2 MB)
  float* Xenc   = ws + 0;                     // 8,388,608
  float* scra   = ws + 8388608;               // scratch region (1,048,576)
  float* xemb   = scra;                       // dead after pre-GEMMs
  float* dqb    = scra + 0;
  float* ctxb   = scra + 131072;
  float* catb   = scra + 262144;
  float* attno  = scra + 524288;
  float* cseq   = scra + 655360;
  float* rowlog = scra + 786432;
  unsigned short* Abf = (unsigned short*)(scra + 786944);  // 131072 ushort = 32768 slots
  float* demb   = ws + 9437184;
  float* Xdec   = ws + 9502720;
  unsigned* Upk2E = (unsigned*)(ws + 10027008);  // 131072 uints
  unsigned* Upk2D = (unsigned*)(ws + 10158080);
  float* encO   = ws + 10289152;              // 2,097,152
  float* ehc    = ws + 12386304;
  float* h0c0   = ws + 12402688;
  float* decO   = ws + 12419072;
  float* cp     = ws + 0;                     // reuse Xenc region

  float* sh  = out + (size_t)B_ * T_ * VO_;
  float* scf = sh + B_ * HD_;

  hipLaunchKernelGGL(packU2_kernel, dim3(512), dim3(256), 0, stream, Uenc, Upk2E);
  hipLaunchKernelGGL(packU2_kernel, dim3(512), dim3(256), 0, stream, Udec, Upk2D);
  hipLaunchKernelGGL(embed_kernel, dim3(B_ * S_), dim3(E_), 0, stream, x, emb, xemb);
  hipLaunchKernelGGL(embed_kernel, dim3(B_ * T_), dim3(E_), 0, stream, decx, emb, demb);
  hipLaunchKernelGGL(gemm_f32, dim3(16, 128), dim3(256), 0, stream,
                     xemb, Wenc, benc, Xenc, B_ * S_, 1024, 128, 1024, 0);
  hipLaunchKernelGGL(gemm_f32, dim3(16, 8), dim3(256), 0, stream,
                     demb, Wdec, bdec, Xdec, B_ * T_, 1024, 128, 1024, 0);
  hipLaunchKernelGGL(lstm_rec2, dim3(B_), dim3(1024), 0, stream,
                     Xenc, Upk2E, (const float*)nullptr, (const float*)nullptr,
                     encO, ehc, ehc + 32 * 256, S_);
  hipLaunchKernelGGL(gemm_f32, dim3(4, 1), dim3(256), 0, stream,
                     ehc, We2d, be2d, h0c0, 64, 256, 256, 256, 0);
  hipLaunchKernelGGL(lstm_rec2, dim3(B_), dim3(1024), 0, stream,
                     Xdec, Upk2D, h0c0, h0c0 + 32 * 256, decO, sh, scf, T_);
  hipLaunchKernelGGL(gemm_f32, dim3(4, 8), dim3(256), 0, stream,
                     decO, Wattn, (const float*)nullptr, dqb, B_ * T_, 256, 256, 256, 0);
  hipLaunchKernelGGL(attn_kernel, dim3(B_ * T_), dim3(256), 0, stream, dqb, encO, xlen, ctxb);
  hipLaunchKernelGGL(concat_kernel, dim3(1024), dim3(256), 0, stream, ctxb, decO, catb);
  hipLaunchKernelGGL(gemm_f32, dim3(4, 8), dim3(256), 0, stream,
                     catb, Wout, bout, attno, B_ * T_, 256, 512, 256, 1);
  hipLaunchKernelGGL(gemm_f32, dim3(4, 128), dim3(256), 0, stream,
                     encO, Wcopy, bcopy, cp, B_ * S_, 256, 256, 256, 1);
  hipLaunchKernelGGL(f2bf_kernel, dim3(512), dim3(256), 0, stream, attno, Abf, B_ * T_ * 256);
  hipLaunchKernelGGL(gen_mfma, dim3(782, 8), dim3(256), 0, stream, Abf, Wgen, out);
  hipLaunchKernelGGL(pad_kernel, dim3(200), dim3(256), 0, stream, out);
  hipLaunchKernelGGL(copyseq_kernel, dim3(B_ * T_), dim3(256), 0, stream, attno, cp, xlen, cseq);
  hipLaunchKernelGGL(scatter_kernel, dim3(512), dim3(256), 0, stream, cseq, xoov, out);
  hipLaunchKernelGGL(rowsum_kernel, dim3(B_ * T_), dim3(256), 0, stream, out, rowlog);
  hipLaunchKernelGGL(finalize_kernel, dim3((B_ * T_ * VO_ + 255) / 256), dim3(256), 0, stream,
                     out, rowlog);
}